// Round 1
// baseline (273.864 us; speedup 1.0000x reference)
//
#include <hip/hip_runtime.h>
#include <hip/hip_bf16.h>

// QuantizedEmbedding: out[r, d] = code[qw[x[r], d]] * absmax[(x[r]*D + d) >> 12]
// One block per gathered row; 256 threads x 4 elements = 1024 = D.
// code table (256 fp32, 1 KB) staged in LDS; quant codes read as int4 (16B/lane);
// output written as float4 (16B/lane). absmax is one broadcast load per thread.

__global__ __launch_bounds__(256) void qembed_kernel(
    const int* __restrict__ x,          // [n_rows] gathered indices
    const int* __restrict__ qw,         // [V, D] int32 codes 0..255
    const float* __restrict__ absmax,   // [n_blocks] per-4096-block scales
    const float* __restrict__ code,     // [256] codebook
    float* __restrict__ out,            // [n_rows, D]
    int D)
{
    __shared__ float lcode[256];
    lcode[threadIdx.x] = code[threadIdx.x];
    __syncthreads();

    const int row = blockIdx.x;
    const int v = x[row];                       // broadcast load (same addr all lanes)
    const long long base = (long long)v * (long long)D;
    const long long obase = (long long)row * (long long)D;

    // Each thread covers 4 consecutive elements; stride 1024 covers D per iter.
    for (int d = threadIdx.x * 4; d < D; d += 256 * 4) {
        // All 4 elements share one absmax block: group start is 4-aligned and
        // block boundary (4096) is a multiple of 4.
        const float am = absmax[(base + d) >> 12];

        const int4 q = *reinterpret_cast<const int4*>(qw + base + d);

        float4 o;
        o.x = lcode[q.x & 0xFF] * am;
        o.y = lcode[q.y & 0xFF] * am;
        o.z = lcode[q.z & 0xFF] * am;
        o.w = lcode[q.w & 0xFF] * am;

        *reinterpret_cast<float4*>(out + obase + d) = o;
    }
}

extern "C" void kernel_launch(void* const* d_in, const int* in_sizes, int n_in,
                              void* d_out, int out_size, void* d_ws, size_t ws_size,
                              hipStream_t stream) {
    const int*   x      = (const int*)d_in[0];    // [B*S] indices
    const int*   qw     = (const int*)d_in[1];    // [V*D] int32 codes
    const float* absmax = (const float*)d_in[2];  // [n_blocks]
    const float* code   = (const float*)d_in[3];  // [256]
    float*       out    = (float*)d_out;

    const int n_rows = in_sizes[0];               // 16384
    const int D = out_size / n_rows;              // 1024

    qembed_kernel<<<n_rows, 256, 0, stream>>>(x, qw, absmax, code, out, D);
}